// Round 2
// baseline (608.099 us; speedup 1.0000x reference)
//
#include <hip/hip_runtime.h>
#include <math.h>

#define NUM_CLASSES 100000
#define EMB 512
#define BATCH 512
#define BN 64
#define NBLK ((NUM_CLASSES + BN - 1) / BN)   /* 1563 */
#define NPART (NBLK * 2)                     /* 3126 partials per row */
#define NPAD  (NBLK * BN)                    /* 100032 padded classes */
#define GRID_MAIN 256

// ArcFace constants (margin m=0.3, scale s=120)
#define S_SCALE 120.0f
#define COS_M   0.9553364891256061f
#define SIN_M   0.29552020666133955f
#define TH_C   (-0.9553364891256061f)        /* cos(pi - m) */
#define MM_C    0.08865606199840187f         /* sin(pi - m) * m */

typedef short bf8 __attribute__((ext_vector_type(8)));   // 8 x bf16 (4 VGPRs)
typedef float f4  __attribute__((ext_vector_type(4)));   // MFMA accumulator

__device__ __forceinline__ unsigned short f2bf(float f) {
    union { float f; unsigned u; } a; a.f = f;
    unsigned r = a.u + 0x7fffu + ((a.u >> 16) & 1u);     // round-nearest-even
    return (unsigned short)(r >> 16);
}

// ---------------------------------------------------------------------------
// Kernel 1: L2-normalize rows of x (f32) -> bf16, one wave per row.
// ---------------------------------------------------------------------------
__global__ __launch_bounds__(256) void k_normx(const float* __restrict__ x,
                                               unsigned short* __restrict__ xb) {
    int row  = blockIdx.x * 4 + (threadIdx.x >> 6);
    int lane = threadIdx.x & 63;
    const float4* xr = (const float4*)(x + (size_t)row * EMB);
    float4 a = xr[lane * 2];
    float4 b = xr[lane * 2 + 1];
    float ss = a.x*a.x + a.y*a.y + a.z*a.z + a.w*a.w
             + b.x*b.x + b.y*b.y + b.z*b.z + b.w*b.w;
#pragma unroll
    for (int d = 1; d < 64; d <<= 1) ss += __shfl_xor(ss, d);
    float rn = 1.0f / fmaxf(sqrtf(ss), 1e-12f);
    int4 o;
    o.x = f2bf(a.x * rn) | (f2bf(a.y * rn) << 16);
    o.y = f2bf(a.z * rn) | (f2bf(a.w * rn) << 16);
    o.z = f2bf(b.x * rn) | (f2bf(b.y * rn) << 16);
    o.w = f2bf(b.z * rn) | (f2bf(b.w * rn) << 16);
    ((int4*)(xb + (size_t)row * EMB))[lane] = o;
}

// ---------------------------------------------------------------------------
// Prep (path 1): W f32 -> normalized bf16 Wb, pre-swizzled so that linear
// global_load_lds staging lands bank-conflict-free for the B-frag ds_reads.
// One wave per class; classes >= NUM_CLASSES zero-filled.
// ---------------------------------------------------------------------------
__global__ __launch_bounds__(256) void k_prep1(const float* __restrict__ W,
                                               unsigned short* __restrict__ Wb) {
    int w    = blockIdx.x * 4 + (threadIdx.x >> 6);   // class id, < NPAD
    int lane = threadIdx.x & 63;
    float4 a = make_float4(0.f,0.f,0.f,0.f), b = a;
    if (w < NUM_CLASSES) {
        const float4* r = (const float4*)(W + (size_t)w * EMB);
        a = r[lane * 2];
        b = r[lane * 2 + 1];
    }
    float ss = a.x*a.x + a.y*a.y + a.z*a.z + a.w*a.w
             + b.x*b.x + b.y*b.y + b.z*b.z + b.w*b.w;
#pragma unroll
    for (int d = 1; d < 64; d <<= 1) ss += __shfl_xor(ss, d);
    float rn = (w < NUM_CLASSES) ? 1.0f / fmaxf(sqrtf(ss), 1e-12f) : 0.0f;
    uint4 o;
    o.x = f2bf(a.x*rn) | (f2bf(a.y*rn) << 16);
    o.y = f2bf(a.z*rn) | (f2bf(a.w*rn) << 16);
    o.z = f2bf(b.x*rn) | (f2bf(b.y*rn) << 16);
    o.w = f2bf(b.z*rn) | (f2bf(b.w*rn) << 16);
    // lane's 8 bf16 = 16B chunk index 'lane'; store at swizzled chunk pos
    *(uint4*)((char*)Wb + (size_t)w * 1024 + ((unsigned)(lane ^ (w & 7)) << 4)) = o;
}

// ---------------------------------------------------------------------------
// Prep (path 2 fallback): per-class 1/||W|| only.
// ---------------------------------------------------------------------------
__global__ __launch_bounds__(256) void k_prep2(const float* __restrict__ W,
                                               float* __restrict__ rnorm) {
    int w    = blockIdx.x * 4 + (threadIdx.x >> 6);
    int lane = threadIdx.x & 63;
    if (w >= NUM_CLASSES) return;
    const float4* r = (const float4*)(W + (size_t)w * EMB);
    float4 a = r[lane * 2];
    float4 b = r[lane * 2 + 1];
    float ss = a.x*a.x + a.y*a.y + a.z*a.z + a.w*a.w
             + b.x*b.x + b.y*b.y + b.z*b.z + b.w*b.w;
#pragma unroll
    for (int d = 1; d < 64; d <<= 1) ss += __shfl_xor(ss, d);
    if (lane == 0) rnorm[w] = 1.0f / fmaxf(sqrtf(ss), 1e-12f);
}

// ---------------------------------------------------------------------------
// Main kernel, persistent + double-buffered LDS.
// 256 blocks x 512 threads (8 waves = 4 M-bands x 2 N-halves).
// Per chunk: prefetch chunk+GRID into Wl[buf^1], MFMA on Wl[buf], 1 barrier.
// PATH 1: Wb bf16 staged via global_load_lds (norm+swizzle pre-baked).
// PATH 2: W f32 reg-staged, *rnorm, converted, swizzled ds_write.
// ---------------------------------------------------------------------------
template<int PATH>
__global__ __launch_bounds__(512, 2) void k_main(
        const float* __restrict__ W, const unsigned short* __restrict__ Wb,
        const float* __restrict__ rnorm, const unsigned short* __restrict__ xb,
        const long long* __restrict__ label, float2* __restrict__ pms,
        float* __restrict__ tgt) {
    __shared__ __align__(16) unsigned short Wl[2][BN * EMB];  // 2 x 64 KiB
    __shared__ int lab[BATCH];

    const int tid  = threadIdx.x;
    const int lane = tid & 63;
    const int wid  = tid >> 6;
    const int band = wid >> 1;   // M band: rows band*128 .. +128
    const int half = wid & 1;    // N half: classes half*32 .. +32
    const int l15  = lane & 15;
    const int lg   = lane >> 4;

    auto STAGE = [&](int ci, int b) {
        if constexpr (PATH == 1) {
            const char* src = (const char*)Wb + (size_t)ci * (BN * EMB * 2);
#pragma unroll
            for (int i = 0; i < 8; ++i) {
                int roff = (i * 8 + wid) << 10;   // 1 KiB per wave-row
                __builtin_amdgcn_global_load_lds(
                    (const __attribute__((address_space(1))) unsigned int*)(src + roff + lane * 16),
                    (__attribute__((address_space(3))) unsigned int*)((char*)&Wl[b][0] + roff),
                    16, 0, 0);
            }
        } else {
            const float4* W4 = (const float4*)W;
#pragma unroll
            for (int i = 0; i < 16; ++i) {
                int lin = i * 512 + tid;
                int cc  = lin >> 7;
                int kv  = lin & 127;
                int c   = ci * BN + cc;
                float4 v = make_float4(0.f,0.f,0.f,0.f);
                float rn = 0.0f;
                if (c < NUM_CLASSES) { v = W4[(size_t)c * 128 + kv]; rn = rnorm[c]; }
                int boff = cc * 1024 + ((kv * 8) ^ ((cc & 7) << 4));
                *(uint2*)((char*)&Wl[b][0] + boff) = make_uint2(
                    f2bf(v.x*rn) | (f2bf(v.y*rn) << 16),
                    f2bf(v.z*rn) | (f2bf(v.w*rn) << 16));
            }
        }
    };

    lab[tid] = (int)label[tid];
    STAGE(blockIdx.x, 0);
    __syncthreads();

    const int rb0 = half * 32 + l15;       // B-frag class rows (within chunk)
    const int rb1 = rb0 + 16;
    const int sw  = (l15 & 7) << 4;        // swizzle (rb0&7 == rb1&7 == l15&7)
    const unsigned short* xp = xb + (size_t)(band * 128 + l15) * EMB;

    int buf = 0;
    for (int ci = blockIdx.x; ci < NBLK; ci += GRID_MAIN) {
        int cn = ci + GRID_MAIN;
        if (cn < NBLK) STAGE(cn, buf ^ 1);

        const char* WlB = (const char*)&Wl[buf][0];
        f4 acc[8][2];
#pragma unroll
        for (int mf = 0; mf < 8; ++mf)
#pragma unroll
            for (int nf = 0; nf < 2; ++nf)
#pragma unroll
                for (int i = 0; i < 4; ++i) acc[mf][nf][i] = 0.0f;

        for (int k0 = 0; k0 < EMB; k0 += 32) {
            int kb = (k0 + lg * 8) * 2;    // byte offset of lane's 16B in a row
            bf8 b0 = *(const bf8*)(WlB + rb0 * 1024 + (kb ^ sw));
            bf8 b1 = *(const bf8*)(WlB + rb1 * 1024 + (kb ^ sw));
#pragma unroll
            for (int mf = 0; mf < 8; ++mf) {
                bf8 a = *(const bf8*)(xp + mf * 16 * EMB + k0 + lg * 8);
                acc[mf][0] = __builtin_amdgcn_mfma_f32_16x16x32_bf16(a, b0, acc[mf][0], 0, 0, 0);
                acc[mf][1] = __builtin_amdgcn_mfma_f32_16x16x32_bf16(a, b1, acc[mf][1], 0, 0, 0);
            }
        }

        // ---- epilogue: cosine -> margin -> online softmax partial ----
        const int c0 = ci * BN;
        const int cA = c0 + half * 32 + l15;
        const int cB = cA + 16;
        const int p  = ci * 2 + half;

#pragma unroll
        for (int mf = 0; mf < 8; ++mf) {
            float v0a[4], v1a[4], mx[4], sm[4];
#pragma unroll
            for (int i = 0; i < 4; ++i) {
                int m  = band * 128 + mf * 16 + lg * 4 + i;   // C/D row mapping
                int lb = lab[m];
                float c0v = acc[mf][0][i];   // cosine (norms pre-baked)
                float c1v = acc[mf][1][i];
                float v0 = S_SCALE * c0v;
                float v1 = S_SCALE * c1v;
                if (cA == lb) {
                    float sine = sqrtf(fmaxf(0.f, 1.f - c0v * c0v));
                    float phi  = c0v * COS_M - sine * SIN_M;
                    if (!(c0v > TH_C)) phi = c0v - MM_C;
                    v0 = S_SCALE * phi;
                    tgt[m] = v0;
                }
                if (cB == lb) {
                    float sine = sqrtf(fmaxf(0.f, 1.f - c1v * c1v));
                    float phi  = c1v * COS_M - sine * SIN_M;
                    if (!(c1v > TH_C)) phi = c1v - MM_C;
                    v1 = S_SCALE * phi;
                    tgt[m] = v1;
                }
                if (cA >= NUM_CLASSES) v0 = -1e30f;   // tail-block padding
                if (cB >= NUM_CLASSES) v1 = -1e30f;
                v0a[i] = v0; v1a[i] = v1;
                mx[i] = fmaxf(v0, v1);
            }
#pragma unroll
            for (int d = 1; d < 16; d <<= 1)
#pragma unroll
                for (int i = 0; i < 4; ++i) mx[i] = fmaxf(mx[i], __shfl_xor(mx[i], d));
#pragma unroll
            for (int i = 0; i < 4; ++i)
                sm[i] = __expf(v0a[i] - mx[i]) + __expf(v1a[i] - mx[i]);
#pragma unroll
            for (int d = 1; d < 16; d <<= 1)
#pragma unroll
                for (int i = 0; i < 4; ++i) sm[i] += __shfl_xor(sm[i], d);
            if (l15 == 0) {
#pragma unroll
                for (int i = 0; i < 4; ++i) {
                    int m = band * 128 + mf * 16 + lg * 4 + i;
                    pms[(size_t)m * NPART + p] = make_float2(mx[i], sm[i]);
                }
            }
        }

        __syncthreads();   // prefetch landed + all waves done with Wl[buf]
        buf ^= 1;
    }
}

// ---------------------------------------------------------------------------
// Kernel: merge 3126 (max,sum) partials per row -> loss[m] = LSE - tgt[m]
// ---------------------------------------------------------------------------
__global__ __launch_bounds__(256) void k_lse(const float2* __restrict__ pms,
                                             const float* __restrict__ tgt,
                                             float* __restrict__ loss) {
    int m = blockIdx.x, t = threadIdx.x;
    float M = -1e38f, Ssum = 0.f;
    for (int p = t; p < NPART; p += 256) {
        float2 v = pms[(size_t)m * NPART + p];
        float nM = fmaxf(M, v.x);
        Ssum = Ssum * __expf(M - nM) + v.y * __expf(v.x - nM);
        M = nM;
    }
#pragma unroll
    for (int d = 1; d < 64; d <<= 1) {
        float oM = __shfl_xor(M, d), oS = __shfl_xor(Ssum, d);
        float nM = fmaxf(M, oM);
        Ssum = Ssum * __expf(M - nM) + oS * __expf(oM - nM);
        M = nM;
    }
    __shared__ float2 wred[4];
    if ((t & 63) == 0) wred[t >> 6] = make_float2(M, Ssum);
    __syncthreads();
    if (t == 0) {
        M = wred[0].x; Ssum = wred[0].y;
        for (int w = 1; w < 4; ++w) {
            float oM = wred[w].x, oS = wred[w].y;
            float nM = fmaxf(M, oM);
            Ssum = Ssum * __expf(M - nM) + oS * __expf(oM - nM);
            M = nM;
        }
        loss[m] = M + logf(Ssum) - tgt[m];
    }
}

// ---------------------------------------------------------------------------
// Kernel: mean over 512 rows -> scalar
// ---------------------------------------------------------------------------
__global__ __launch_bounds__(512) void k_mean(const float* __restrict__ loss,
                                              float* __restrict__ out) {
    int t = threadIdx.x;
    float v = loss[t];
#pragma unroll
    for (int d = 1; d < 64; d <<= 1) v += __shfl_xor(v, d);
    __shared__ float wred[8];
    if ((t & 63) == 0) wred[t >> 6] = v;
    __syncthreads();
    if (t == 0) {
        float s = 0.f;
        for (int w = 0; w < 8; ++w) s += wred[w];
        out[0] = s / (float)BATCH;
    }
}

extern "C" void kernel_launch(void* const* d_in, const int* in_sizes, int n_in,
                              void* d_out, int out_size, void* d_ws, size_t ws_size,
                              hipStream_t stream) {
    const float*     x     = (const float*)d_in[0];
    const long long* label = (const long long*)d_in[1];
    const float*     W     = (const float*)d_in[2];
    float*           out   = (float*)d_out;

    // workspace layout
    char* ws = (char*)d_ws;
    unsigned short* xb  = (unsigned short*)ws;              // 524288 B
    float*          tgt = (float*)(ws + 524288);            // 2048 B
    float*          lss = (float*)(ws + 524288 + 2048);     // 2048 B
    float2*         pms = (float2*)(ws + 528384);           // 512*3126*8 = 12804096 B
    char*           ext = ws + 528384 + 12804096;           // 13332480
    const size_t WB_BYTES = (size_t)NPAD * EMB * 2;         // 102432768
    bool path1 = ws_size >= (size_t)13332480 + WB_BYTES;

    k_normx<<<BATCH / 4, 256, 0, stream>>>(x, xb);
    if (path1) {
        unsigned short* Wb = (unsigned short*)ext;
        k_prep1<<<NPAD / 4, 256, 0, stream>>>(W, Wb);
        k_main<1><<<GRID_MAIN, 512, 0, stream>>>(W, Wb, nullptr, xb, label, pms, tgt);
    } else {
        float* rnorm = (float*)ext;
        k_prep2<<<NUM_CLASSES / 4, 256, 0, stream>>>(W, rnorm);
        k_main<2><<<GRID_MAIN, 512, 0, stream>>>(W, nullptr, rnorm, xb, label, pms, tgt);
    }
    k_lse <<<BATCH, 256, 0, stream>>>(pms, tgt, lss);
    k_mean<<<1,     512, 0, stream>>>(lss, out);
}

// Round 3
// 390.304 us; speedup vs baseline: 1.5580x; 1.5580x over previous
//
#include <hip/hip_runtime.h>
#include <math.h>

#define NUM_CLASSES 100000
#define EMB 512
#define BATCH 512
#define BN 64
#define NBLK ((NUM_CLASSES + BN - 1) / BN)   /* 1563 chunks of 64 classes */
#define GRID_MAIN 256
#define RBLK 64
#define QRED ((NBLK + RBLK - 1) / RBLK)      /* 25 partials per k_red block */

// ArcFace constants (margin m=0.3, scale s=120)
#define S_SCALE 120.0f
#define COS_M   0.9553364891256061f
#define SIN_M   0.29552020666133955f
#define TH_C   (-0.9553364891256061f)        /* cos(pi - m) */
#define MM_C    0.08865606199840187f         /* sin(pi - m) * m */

typedef short bf8 __attribute__((ext_vector_type(8)));   // 8 x bf16 (4 VGPRs)
typedef float f4  __attribute__((ext_vector_type(4)));   // MFMA accumulator

__device__ __forceinline__ unsigned short f2bf(float f) {
    union { float f; unsigned u; } a; a.f = f;
    unsigned r = a.u + 0x7fffu + ((a.u >> 16) & 1u);     // round-nearest-even
    return (unsigned short)(r >> 16);
}

// ---------------------------------------------------------------------------
// Kernel 1: L2-normalize rows of x (f32) -> bf16, one wave per row.
// ---------------------------------------------------------------------------
__global__ __launch_bounds__(256) void k_normx(const float* __restrict__ x,
                                               unsigned short* __restrict__ xb) {
    int row  = blockIdx.x * 4 + (threadIdx.x >> 6);
    int lane = threadIdx.x & 63;
    const float4* xr = (const float4*)(x + (size_t)row * EMB);
    float4 a = xr[lane * 2];
    float4 b = xr[lane * 2 + 1];
    float ss = a.x*a.x + a.y*a.y + a.z*a.z + a.w*a.w
             + b.x*b.x + b.y*b.y + b.z*b.z + b.w*b.w;
#pragma unroll
    for (int d = 1; d < 64; d <<= 1) ss += __shfl_xor(ss, d);
    float rn = 1.0f / fmaxf(sqrtf(ss), 1e-12f);
    int4 o;
    o.x = f2bf(a.x * rn) | (f2bf(a.y * rn) << 16);
    o.y = f2bf(a.z * rn) | (f2bf(a.w * rn) << 16);
    o.z = f2bf(b.x * rn) | (f2bf(b.y * rn) << 16);
    o.w = f2bf(b.z * rn) | (f2bf(b.w * rn) << 16);
    ((int4*)(xb + (size_t)row * EMB))[lane] = o;
}

// ---------------------------------------------------------------------------
// Main kernel: persistent, single-pass over W (f32 read once).
// 256 blocks x 512 threads (8 waves). Per 64-class chunk:
//   stage: 8 lanes/class load 16 float4 each, local f32 sumsq (3 shuffles/cls),
//          convert to UNnormalized bf16 -> swizzled LDS; rsqrt applied in epi.
//   MFMA:  wave = 64 rows (band=wid) x 64 classes; mf=4 x nf=4, 16x16x32 bf16.
//   epi:   *rsqrt(ssq) -> margin at label col -> one online-softmax partial
//          per (row, chunk), written coalesced to pms[chunk][row].
// Single LDS buffer (66 KiB) -> 2 blocks/CU; stage of one block overlaps
// compute of the other.
// ---------------------------------------------------------------------------
__global__ __launch_bounds__(512, 4) void k_main(
        const float* __restrict__ W, const unsigned short* __restrict__ xb,
        const long long* __restrict__ label, float2* __restrict__ pms,
        float* __restrict__ tgt) {
    __shared__ __align__(16) unsigned short Wl[BN * EMB];   // 64 KiB
    __shared__ float ssq[BN];
    __shared__ int   lab[BATCH];

    const int tid  = threadIdx.x;
    const int lane = tid & 63;
    const int wid  = tid >> 6;        // band: rows wid*64 .. +64
    const int l15  = lane & 15;
    const int lg   = lane >> 4;

    lab[tid] = (int)label[tid];

    const int sc = tid >> 3;          // staging: class within chunk (0..63)
    const int sj = tid & 7;           // staging: 8 threads per class
    const float4* W4 = (const float4*)W;

    const int sw = (l15 & 7) << 4;    // B-frag read swizzle
    const unsigned short* xp = xb + (size_t)(wid * 64 + l15) * EMB;

    for (int ci = blockIdx.x; ci < NBLK; ci += GRID_MAIN) {
        const int c0 = ci * BN;

        // ---- stage 64 classes x 512 f32 (128 KiB) ----
        {
            int  c  = c0 + sc;
            bool ok = (c < NUM_CLASSES);
            const float4* src = W4 + (size_t)c * (EMB / 4);
            float s = 0.0f;
#pragma unroll
            for (int t = 0; t < 16; ++t) {
                float4 v = ok ? src[sj + 8 * t] : make_float4(0.f, 0.f, 0.f, 0.f);
                s += v.x*v.x + v.y*v.y + v.z*v.z + v.w*v.w;
                int kv = sj + 8 * t;   // float4 index within row (8B bf16 chunk)
                *(uint2*)((char*)Wl + sc * 1024 + ((kv * 8) ^ ((sc & 7) << 4))) =
                    make_uint2(f2bf(v.x) | (f2bf(v.y) << 16),
                               f2bf(v.z) | (f2bf(v.w) << 16));
            }
            s += __shfl_xor(s, 1); s += __shfl_xor(s, 2); s += __shfl_xor(s, 4);
            if (sj == 0) ssq[sc] = s;
        }
        __syncthreads();

        // ---- MFMA: 64 rows x 64 classes per wave ----
        f4 acc[4][4];
#pragma unroll
        for (int mf = 0; mf < 4; ++mf)
#pragma unroll
            for (int nf = 0; nf < 4; ++nf)
#pragma unroll
                for (int i = 0; i < 4; ++i) acc[mf][nf][i] = 0.0f;

        const char* WlB = (const char*)Wl;
        for (int k0 = 0; k0 < EMB; k0 += 32) {
            int kb = (k0 + lg * 8) * 2;
            bf8 b0 = *(const bf8*)(WlB + (0 * 16 + l15) * 1024 + (kb ^ sw));
            bf8 b1 = *(const bf8*)(WlB + (1 * 16 + l15) * 1024 + (kb ^ sw));
            bf8 b2 = *(const bf8*)(WlB + (2 * 16 + l15) * 1024 + (kb ^ sw));
            bf8 b3 = *(const bf8*)(WlB + (3 * 16 + l15) * 1024 + (kb ^ sw));
#pragma unroll
            for (int mf = 0; mf < 4; ++mf) {
                bf8 a = *(const bf8*)(xp + mf * 16 * EMB + k0 + lg * 8);
                acc[mf][0] = __builtin_amdgcn_mfma_f32_16x16x32_bf16(a, b0, acc[mf][0], 0, 0, 0);
                acc[mf][1] = __builtin_amdgcn_mfma_f32_16x16x32_bf16(a, b1, acc[mf][1], 0, 0, 0);
                acc[mf][2] = __builtin_amdgcn_mfma_f32_16x16x32_bf16(a, b2, acc[mf][2], 0, 0, 0);
                acc[mf][3] = __builtin_amdgcn_mfma_f32_16x16x32_bf16(a, b3, acc[mf][3], 0, 0, 0);
            }
        }

        // ---- epilogue ----
        float rn[4];
#pragma unroll
        for (int nf = 0; nf < 4; ++nf)
            rn[nf] = 1.0f / fmaxf(sqrtf(ssq[nf * 16 + l15]), 1e-12f);

#pragma unroll
        for (int mf = 0; mf < 4; ++mf) {
#pragma unroll
            for (int i = 0; i < 4; ++i) {
                int m  = wid * 64 + mf * 16 + lg * 4 + i;   // C/D row mapping
                int lb = lab[m];
                float vv[4], mx = -1e38f;
#pragma unroll
                for (int nf = 0; nf < 4; ++nf) {
                    int   c  = c0 + nf * 16 + l15;
                    float cv = acc[mf][nf][i] * rn[nf];
                    float v  = S_SCALE * cv;
                    if (c == lb) {
                        float sine = sqrtf(fmaxf(0.f, 1.f - cv * cv));
                        float phi  = cv * COS_M - sine * SIN_M;
                        if (!(cv > TH_C)) phi = cv - MM_C;
                        v = S_SCALE * phi;
                        tgt[m] = v;
                    }
                    if (c >= NUM_CLASSES) v = -1e30f;       // tail-chunk padding
                    vv[nf] = v;
                    mx = fmaxf(mx, v);
                }
#pragma unroll
                for (int d = 1; d < 16; d <<= 1) mx = fmaxf(mx, __shfl_xor(mx, d));
                float sm = __expf(vv[0] - mx) + __expf(vv[1] - mx)
                         + __expf(vv[2] - mx) + __expf(vv[3] - mx);
#pragma unroll
                for (int d = 1; d < 16; d <<= 1) sm += __shfl_xor(sm, d);
                if (l15 == 0)
                    pms[(size_t)ci * BATCH + m] = make_float2(mx, sm);
            }
        }
        __syncthreads();   // Wl/ssq reuse next chunk
    }
}

// ---------------------------------------------------------------------------
// k_red: merge partials over chunk-slices, coalesced. part[b][m].
// ---------------------------------------------------------------------------
__global__ __launch_bounds__(512) void k_red(const float2* __restrict__ pms,
                                             float2* __restrict__ part) {
    int t = threadIdx.x, b = blockIdx.x;
    float M = -1e38f, Ssum = 0.f;
    int p0 = b * QRED;
    int p1 = p0 + QRED < NBLK ? p0 + QRED : NBLK;
    for (int p = p0; p < p1; ++p) {
        float2 v = pms[(size_t)p * BATCH + t];
        float nM = fmaxf(M, v.x);
        Ssum = Ssum * __expf(M - nM) + v.y * __expf(v.x - nM);
        M = nM;
    }
    part[b * BATCH + t] = make_float2(M, Ssum);
}

// ---------------------------------------------------------------------------
// k_fin: per-row final merge -> loss -> mean -> out[0].
// ---------------------------------------------------------------------------
__global__ __launch_bounds__(512) void k_fin(const float2* __restrict__ part,
                                             const float* __restrict__ tgt,
                                             float* __restrict__ out) {
    int t = threadIdx.x;
    float M = -1e38f, Ssum = 0.f;
    for (int b = 0; b < RBLK; ++b) {
        float2 v = part[b * BATCH + t];
        float nM = fmaxf(M, v.x);
        Ssum = Ssum * __expf(M - nM) + v.y * __expf(v.x - nM);
        M = nM;
    }
    float loss = M + logf(Ssum) - tgt[t];
#pragma unroll
    for (int d = 1; d < 64; d <<= 1) loss += __shfl_xor(loss, d);
    __shared__ float wred[8];
    if ((t & 63) == 0) wred[t >> 6] = loss;
    __syncthreads();
    if (t == 0) {
        float s = 0.f;
        for (int w = 0; w < 8; ++w) s += wred[w];
        out[0] = s / (float)BATCH;
    }
}

extern "C" void kernel_launch(void* const* d_in, const int* in_sizes, int n_in,
                              void* d_out, int out_size, void* d_ws, size_t ws_size,
                              hipStream_t stream) {
    const float*     x     = (const float*)d_in[0];
    const long long* label = (const long long*)d_in[1];
    const float*     W     = (const float*)d_in[2];
    float*           out   = (float*)d_out;

    // workspace layout (~7.2 MB)
    char* ws = (char*)d_ws;
    unsigned short* xb   = (unsigned short*)ws;                 // 524288 B
    float*          tgt  = (float*)(ws + 524288);               // 2048 B
    float2*         pms  = (float2*)(ws + 526336);              // NBLK*512*8 = 6402048 B
    float2*         part = (float2*)(ws + 526336 + 6402048);    // 64*512*8 = 262144 B

    k_normx<<<BATCH / 4, 256, 0, stream>>>(x, xb);
    k_main <<<GRID_MAIN, 512, 0, stream>>>(W, xb, label, pms, tgt);
    k_red  <<<RBLK,      512, 0, stream>>>(pms, part);
    k_fin  <<<1,         512, 0, stream>>>(part, tgt, out);
}

// Round 4
// 330.963 us; speedup vs baseline: 1.8374x; 1.1793x over previous
//
#include <hip/hip_runtime.h>
#include <math.h>

#define NUM_CLASSES 100000
#define EMB 512
#define BATCH 512
#define BN 64
#define NBLK ((NUM_CLASSES + BN - 1) / BN)   /* 1563 chunks of 64 classes */
#define GRID_MAIN 512                        /* 2 blocks/CU on 256 CUs */
#define RBLK 64
#define QRED (GRID_MAIN / RBLK)              /* 8 partials per k_red block */

// ArcFace constants (margin m=0.3, scale s=120)
#define S_SCALE 120.0f
#define COS_M   0.9553364891256061f
#define SIN_M   0.29552020666133955f
#define TH_C   (-0.9553364891256061f)        /* cos(pi - m) */
#define MM_C    0.08865606199840187f         /* sin(pi - m) * m */

typedef short bf8   __attribute__((ext_vector_type(8)));  // 8 x bf16 (4 VGPRs)
typedef float f4    __attribute__((ext_vector_type(4)));  // MFMA accumulator
typedef float f32x4 __attribute__((ext_vector_type(4)));  // for nontemporal ld

__device__ __forceinline__ unsigned short f2bf(float f) {
    union { float f; unsigned u; } a; a.f = f;
    unsigned r = a.u + 0x7fffu + ((a.u >> 16) & 1u);     // round-nearest-even
    return (unsigned short)(r >> 16);
}

// ---------------------------------------------------------------------------
// Kernel 1: L2-normalize rows of x (f32) -> bf16, one wave per row.
// ---------------------------------------------------------------------------
__global__ __launch_bounds__(256) void k_normx(const float* __restrict__ x,
                                               unsigned short* __restrict__ xb) {
    int row  = blockIdx.x * 4 + (threadIdx.x >> 6);
    int lane = threadIdx.x & 63;
    const float4* xr = (const float4*)(x + (size_t)row * EMB);
    float4 a = xr[lane * 2];
    float4 b = xr[lane * 2 + 1];
    float ss = a.x*a.x + a.y*a.y + a.z*a.z + a.w*a.w
             + b.x*b.x + b.y*b.y + b.z*b.z + b.w*b.w;
#pragma unroll
    for (int d = 1; d < 64; d <<= 1) ss += __shfl_xor(ss, d);
    float rn = 1.0f / fmaxf(sqrtf(ss), 1e-12f);
    int4 o;
    o.x = f2bf(a.x * rn) | (f2bf(a.y * rn) << 16);
    o.y = f2bf(a.z * rn) | (f2bf(a.w * rn) << 16);
    o.z = f2bf(b.x * rn) | (f2bf(b.y * rn) << 16);
    o.w = f2bf(b.z * rn) | (f2bf(b.w * rn) << 16);
    ((int4*)(xb + (size_t)row * EMB))[lane] = o;
}

// ---------------------------------------------------------------------------
// Main kernel: persistent, single pass over W (nontemporal f32, read once).
// 512 blocks x 512 threads (8 waves), ~3 chunks/block, 2 blocks/CU so one
// block's HBM stage overlaps the other's MFMA phase.
// Per 64-class chunk:
//   stage: 8 lanes/class, 16 nontemporal float4 each, local sumsq,
//          unnormalized bf16 -> XOR-swizzled LDS;
//   MFMA:  wave = 64 rows x 64 classes, 16x16x32 bf16, mf=4 x nf=4;
//   epi:   rsqrt(ssq) -> margin at label -> per-row online (M,S) merged into
//          LDS (no per-chunk global writes).
// End: one coalesced 4 KB partial write per block.
// ---------------------------------------------------------------------------
__global__ __launch_bounds__(512, 4) void k_main(
        const float* __restrict__ W, const unsigned short* __restrict__ xb,
        const long long* __restrict__ label, float2* __restrict__ pms,
        float* __restrict__ tgt) {
    __shared__ __align__(16) unsigned short Wl[BN * EMB];   // 64 KiB
    __shared__ float  ssq[BN];
    __shared__ int    lab[BATCH];
    __shared__ float2 msl[BATCH];                           // running (M,S)

    const int tid  = threadIdx.x;
    const int lane = tid & 63;
    const int wid  = tid >> 6;        // band: rows wid*64 .. +64
    const int l15  = lane & 15;
    const int lg   = lane >> 4;

    lab[tid] = (int)label[tid];
    msl[tid] = make_float2(-1e38f, 0.0f);

    const int sc = tid >> 3;          // staging: class within chunk (0..63)
    const int sj = tid & 7;           // staging: 8 threads per class
    const f32x4* W4 = (const f32x4*)W;

    const int sw = (l15 & 7) << 4;    // B-frag read swizzle
    const unsigned short* xp = xb + (size_t)(wid * 64 + l15) * EMB;

    for (int ci = blockIdx.x; ci < NBLK; ci += GRID_MAIN) {
        const int c0 = ci * BN;

        // ---- stage 64 classes x 512 f32 (128 KiB), nontemporal ----
        {
            int  c  = c0 + sc;
            bool ok = (c < NUM_CLASSES);
            const f32x4* src = W4 + (size_t)c * (EMB / 4);
            float s = 0.0f;
#pragma unroll
            for (int t = 0; t < 16; ++t) {
                f32x4 v;
                if (ok) v = __builtin_nontemporal_load(src + sj + 8 * t);
                else    { v[0] = 0.f; v[1] = 0.f; v[2] = 0.f; v[3] = 0.f; }
                s += v[0]*v[0] + v[1]*v[1] + v[2]*v[2] + v[3]*v[3];
                int kv = sj + 8 * t;   // float4 index within row (8B bf16 unit)
                *(uint2*)((char*)Wl + sc * 1024 + ((kv * 8) ^ ((sc & 7) << 4))) =
                    make_uint2(f2bf(v[0]) | (f2bf(v[1]) << 16),
                               f2bf(v[2]) | (f2bf(v[3]) << 16));
            }
            s += __shfl_xor(s, 1); s += __shfl_xor(s, 2); s += __shfl_xor(s, 4);
            if (sj == 0) ssq[sc] = s;
        }
        __syncthreads();

        // ---- MFMA: 64 rows x 64 classes per wave ----
        f4 acc[4][4];
#pragma unroll
        for (int mf = 0; mf < 4; ++mf)
#pragma unroll
            for (int nf = 0; nf < 4; ++nf)
#pragma unroll
                for (int i = 0; i < 4; ++i) acc[mf][nf][i] = 0.0f;

        const char* WlB = (const char*)Wl;
        for (int k0 = 0; k0 < EMB; k0 += 32) {
            int kb = (k0 + lg * 8) * 2;
            bf8 b0 = *(const bf8*)(WlB + (0 * 16 + l15) * 1024 + (kb ^ sw));
            bf8 b1 = *(const bf8*)(WlB + (1 * 16 + l15) * 1024 + (kb ^ sw));
            bf8 b2 = *(const bf8*)(WlB + (2 * 16 + l15) * 1024 + (kb ^ sw));
            bf8 b3 = *(const bf8*)(WlB + (3 * 16 + l15) * 1024 + (kb ^ sw));
#pragma unroll
            for (int mf = 0; mf < 4; ++mf) {
                bf8 a = *(const bf8*)(xp + mf * 16 * EMB + k0 + lg * 8);
                acc[mf][0] = __builtin_amdgcn_mfma_f32_16x16x32_bf16(a, b0, acc[mf][0], 0, 0, 0);
                acc[mf][1] = __builtin_amdgcn_mfma_f32_16x16x32_bf16(a, b1, acc[mf][1], 0, 0, 0);
                acc[mf][2] = __builtin_amdgcn_mfma_f32_16x16x32_bf16(a, b2, acc[mf][2], 0, 0, 0);
                acc[mf][3] = __builtin_amdgcn_mfma_f32_16x16x32_bf16(a, b3, acc[mf][3], 0, 0, 0);
            }
        }

        // ---- epilogue ----
        float rn[4];
#pragma unroll
        for (int nf = 0; nf < 4; ++nf)
            rn[nf] = 1.0f / fmaxf(sqrtf(ssq[nf * 16 + l15]), 1e-12f);

#pragma unroll
        for (int mf = 0; mf < 4; ++mf) {
            float mx[4], sm[4], vv[4][4];
#pragma unroll
            for (int i = 0; i < 4; ++i) {
                int m  = wid * 64 + mf * 16 + lg * 4 + i;   // C/D row mapping
                int lb = lab[m];
                mx[i] = -1e38f;
#pragma unroll
                for (int nf = 0; nf < 4; ++nf) {
                    int   c  = c0 + nf * 16 + l15;
                    float cv = acc[mf][nf][i] * rn[nf];
                    float v  = S_SCALE * cv;
                    if (c == lb) {
                        float sine = sqrtf(fmaxf(0.f, 1.f - cv * cv));
                        float phi  = cv * COS_M - sine * SIN_M;
                        if (!(cv > TH_C)) phi = cv - MM_C;
                        v = S_SCALE * phi;
                        tgt[m] = v;
                    }
                    if (c >= NUM_CLASSES) v = -1e30f;       // tail-chunk pad
                    vv[nf][i] = v;
                    mx[i] = fmaxf(mx[i], v);
                }
            }
#pragma unroll
            for (int d = 1; d < 16; d <<= 1)
#pragma unroll
                for (int i = 0; i < 4; ++i) mx[i] = fmaxf(mx[i], __shfl_xor(mx[i], d));
#pragma unroll
            for (int i = 0; i < 4; ++i)
                sm[i] = __expf(vv[0][i] - mx[i]) + __expf(vv[1][i] - mx[i])
                      + __expf(vv[2][i] - mx[i]) + __expf(vv[3][i] - mx[i]);
#pragma unroll
            for (int d = 1; d < 16; d <<= 1)
#pragma unroll
                for (int i = 0; i < 4; ++i) sm[i] += __shfl_xor(sm[i], d);
            if (l15 == 0) {
#pragma unroll
                for (int i = 0; i < 4; ++i) {
                    int m = wid * 64 + mf * 16 + lg * 4 + i;
                    float2 cur = msl[m];
                    float nM = fmaxf(cur.x, mx[i]);
                    float nS = cur.y * __expf(cur.x - nM)
                             + sm[i] * __expf(mx[i] - nM);
                    msl[m] = make_float2(nM, nS);
                }
            }
        }
        __syncthreads();   // Wl/ssq reused next chunk
    }

    // one coalesced partial write per block
    pms[(size_t)blockIdx.x * BATCH + tid] = msl[tid];
}

// ---------------------------------------------------------------------------
// k_red: merge block partials over slices, coalesced. part[b][m].
// ---------------------------------------------------------------------------
__global__ __launch_bounds__(512) void k_red(const float2* __restrict__ pms,
                                             float2* __restrict__ part) {
    int t = threadIdx.x, b = blockIdx.x;
    float M = -1e38f, Ssum = 0.f;
#pragma unroll
    for (int q = 0; q < QRED; ++q) {
        float2 v = pms[(size_t)(b * QRED + q) * BATCH + t];
        float nM = fmaxf(M, v.x);
        Ssum = Ssum * __expf(M - nM) + v.y * __expf(v.x - nM);
        M = nM;
    }
    part[b * BATCH + t] = make_float2(M, Ssum);
}

// ---------------------------------------------------------------------------
// k_fin: per-row final merge -> loss -> mean -> out[0].
// ---------------------------------------------------------------------------
__global__ __launch_bounds__(512) void k_fin(const float2* __restrict__ part,
                                             const float* __restrict__ tgt,
                                             float* __restrict__ out) {
    int t = threadIdx.x;
    float M = -1e38f, Ssum = 0.f;
    for (int b = 0; b < RBLK; ++b) {
        float2 v = part[b * BATCH + t];
        float nM = fmaxf(M, v.x);
        Ssum = Ssum * __expf(M - nM) + v.y * __expf(v.x - nM);
        M = nM;
    }
    float loss = M + logf(Ssum) - tgt[t];
#pragma unroll
    for (int d = 1; d < 64; d <<= 1) loss += __shfl_xor(loss, d);
    __shared__ float wred[8];
    if ((t & 63) == 0) wred[t >> 6] = loss;
    __syncthreads();
    if (t == 0) {
        float s = 0.f;
        for (int w = 0; w < 8; ++w) s += wred[w];
        out[0] = s / (float)BATCH;
    }
}

extern "C" void kernel_launch(void* const* d_in, const int* in_sizes, int n_in,
                              void* d_out, int out_size, void* d_ws, size_t ws_size,
                              hipStream_t stream) {
    const float*     x     = (const float*)d_in[0];
    const long long* label = (const long long*)d_in[1];
    const float*     W     = (const float*)d_in[2];
    float*           out   = (float*)d_out;

    // workspace layout (~2.9 MB)
    char* ws = (char*)d_ws;
    unsigned short* xb   = (unsigned short*)ws;                 // 524288 B
    float*          tgt  = (float*)(ws + 524288);               // 2048 B
    float2*         pms  = (float2*)(ws + 526336);              // 512*512*8 = 2097152 B
    float2*         part = (float2*)(ws + 526336 + 2097152);    // 64*512*8 = 262144 B

    k_normx<<<BATCH / 4, 256, 0, stream>>>(x, xb);
    k_main <<<GRID_MAIN, 512, 0, stream>>>(W, xb, label, pms, tgt);
    k_red  <<<RBLK,      512, 0, stream>>>(pms, part);
    k_fin  <<<1,         512, 0, stream>>>(part, tgt, out);
}

// Round 5
// 183.872 us; speedup vs baseline: 3.3072x; 1.8000x over previous
//
#include <hip/hip_runtime.h>
#include <math.h>

#define NUM_CLASSES 100000
#define EMB 512
#define BATCH 512
#define BN 64
#define NBLK ((NUM_CLASSES + BN - 1) / BN)   /* 1563 chunks of 64 classes */
#define GRID_MAIN 256                        /* persistent, 1 block/CU */

// ArcFace constants (margin m=0.3, scale s=120)
#define S_SCALE 120.0f
#define COS_M   0.9553364891256061f
#define SIN_M   0.29552020666133955f
#define TH_C   (-0.9553364891256061f)        /* cos(pi - m) */
#define MM_C    0.08865606199840187f         /* sin(pi - m) * m */

typedef short bf8 __attribute__((ext_vector_type(8)));   // 8 x bf16 (4 VGPRs)
typedef float f4  __attribute__((ext_vector_type(4)));   // MFMA accumulator

__device__ __forceinline__ unsigned short f2bf(float f) {
    union { float f; unsigned u; } a; a.f = f;
    unsigned r = a.u + 0x7fffu + ((a.u >> 16) & 1u);     // round-nearest-even
    return (unsigned short)(r >> 16);
}

// ---------------------------------------------------------------------------
// Kernel 1: L2-normalize rows of x (f32) -> bf16, one wave per row.
// ---------------------------------------------------------------------------
__global__ __launch_bounds__(256) void k_normx(const float* __restrict__ x,
                                               unsigned short* __restrict__ xb) {
    int row  = blockIdx.x * 4 + (threadIdx.x >> 6);
    int lane = threadIdx.x & 63;
    const float4* xr = (const float4*)(x + (size_t)row * EMB);
    float4 a = xr[lane * 2];
    float4 b = xr[lane * 2 + 1];
    float ss = a.x*a.x + a.y*a.y + a.z*a.z + a.w*a.w
             + b.x*b.x + b.y*b.y + b.z*b.z + b.w*b.w;
#pragma unroll
    for (int d = 1; d < 64; d <<= 1) ss += __shfl_xor(ss, d);
    float rn = 1.0f / fmaxf(sqrtf(ss), 1e-12f);
    int4 o;
    o.x = f2bf(a.x * rn) | (f2bf(a.y * rn) << 16);
    o.y = f2bf(a.z * rn) | (f2bf(a.w * rn) << 16);
    o.z = f2bf(b.x * rn) | (f2bf(b.y * rn) << 16);
    o.w = f2bf(b.z * rn) | (f2bf(b.w * rn) << 16);
    ((int4*)(xb + (size_t)row * EMB))[lane] = o;
}

// ---------------------------------------------------------------------------
// Kernel 2: exact f32 target logit per row: s*cos and s*phi at the label.
// One wave per row.
// ---------------------------------------------------------------------------
__global__ __launch_bounds__(512) void k_tgt(const float* __restrict__ x,
                                             const float* __restrict__ W,
                                             const long long* __restrict__ label,
                                             float* __restrict__ tcos,
                                             float* __restrict__ tphi) {
    int m    = blockIdx.x * 8 + (threadIdx.x >> 6);
    int lane = threadIdx.x & 63;
    int lb   = (int)label[m];
    const float4* xr = (const float4*)(x + (size_t)m  * EMB);
    const float4* wr = (const float4*)(W + (size_t)lb * EMB);
    float sx = 0.f, sw = 0.f, sd = 0.f;
#pragma unroll
    for (int q = 0; q < 2; ++q) {
        float4 a = xr[lane * 2 + q];
        float4 b = wr[lane * 2 + q];
        sx += a.x*a.x + a.y*a.y + a.z*a.z + a.w*a.w;
        sw += b.x*b.x + b.y*b.y + b.z*b.z + b.w*b.w;
        sd += a.x*b.x + a.y*b.y + a.z*b.z + a.w*b.w;
    }
#pragma unroll
    for (int d = 1; d < 64; d <<= 1) {
        sx += __shfl_xor(sx, d);
        sw += __shfl_xor(sw, d);
        sd += __shfl_xor(sd, d);
    }
    if (lane == 0) {
        float cv = sd / (fmaxf(sqrtf(sx), 1e-12f) * fmaxf(sqrtf(sw), 1e-12f));
        float sine = sqrtf(fmaxf(0.f, 1.f - cv * cv));
        float phi  = cv * COS_M - sine * SIN_M;
        if (!(cv > TH_C)) phi = cv - MM_C;
        tcos[m] = S_SCALE * cv;
        tphi[m] = S_SCALE * phi;
    }
}

// ---------------------------------------------------------------------------
// Main kernel: pure streaming GEMM + per-lane online log-sum-exp.
// 256 blocks x 1024 threads (16 waves, 1 block/CU). Double-buffered 2x64KB
// LDS. Wave tile = 32 rows x 64 classes -> acc = 32 regs/lane, leaving ~90
// VGPRs for software pipelining. No labels, no margin, no per-chunk global
// writes. Per chunk: k-loop (buf) -> issue next-chunk loads -> epilogue
// (online M,S update; hides load latency) -> convert+ds_write (buf^1) ->
// one barrier.
// ---------------------------------------------------------------------------
__global__ __launch_bounds__(1024, 4) void k_main(
        const float* __restrict__ W, const unsigned short* __restrict__ xb,
        float2* __restrict__ pms) {
    __shared__ __align__(16) unsigned short Wl[2][BN * EMB];  // 2 x 64 KiB
    __shared__ float ssq[2][BN];

    const int tid  = threadIdx.x;
    const int lane = tid & 63;
    const int wid  = tid >> 6;         // 0..15; rows wid*32 .. +32
    const int l15  = lane & 15;
    const int lg   = lane >> 4;

    // staging role: 16 threads per class
    const int cc = tid >> 4;           // class within chunk (0..63)
    const int sj = tid & 15;
    const float4* W4 = (const float4*)W;

    const int sw = (l15 & 7) << 4;     // B-frag read swizzle
    const unsigned short* xp = xb + (size_t)(wid * 32 + l15) * EMB;

    // persistent per-lane online-softmax state, per (mf,i)
    float Mr[2][4], Sr[2][4];
#pragma unroll
    for (int mf = 0; mf < 2; ++mf)
#pragma unroll
        for (int i = 0; i < 4; ++i) { Mr[mf][i] = -1e38f; Sr[mf][i] = 0.0f; }

    // ---- prologue: stage chunk blockIdx.x into buf 0 ----
    {
        int   c = blockIdx.x * BN + cc;
        float s = 0.f;
#pragma unroll
        for (int q = 0; q < 8; ++q) {
            int fj = sj + 16 * q;
            float4 v = (c < NUM_CLASSES) ? W4[(size_t)c * 128 + fj]
                                         : make_float4(0.f, 0.f, 0.f, 0.f);
            s += v.x*v.x + v.y*v.y + v.z*v.z + v.w*v.w;
            *(uint2*)((char*)&Wl[0][0] + cc * 1024 + ((fj * 8) ^ ((cc & 7) << 4))) =
                make_uint2(f2bf(v.x) | (f2bf(v.y) << 16),
                           f2bf(v.z) | (f2bf(v.w) << 16));
        }
        s += __shfl_xor(s, 1); s += __shfl_xor(s, 2);
        s += __shfl_xor(s, 4); s += __shfl_xor(s, 8);
        if (sj == 0) ssq[0][cc] = s;
    }
    __syncthreads();

    int buf = 0;
    for (int ci = blockIdx.x; ci < NBLK; ci += GRID_MAIN) {
        // ---- MFMA k-loop on buf: 32 rows x 64 classes per wave ----
        f4 acc[2][4];
#pragma unroll
        for (int mf = 0; mf < 2; ++mf)
#pragma unroll
            for (int nf = 0; nf < 4; ++nf)
#pragma unroll
                for (int i = 0; i < 4; ++i) acc[mf][nf][i] = 0.0f;

        const char* WlB = (const char*)&Wl[buf][0];
#pragma unroll 4
        for (int k0 = 0; k0 < EMB; k0 += 32) {
            int kb = k0 * 2 + lg * 16;
            bf8 b0 = *(const bf8*)(WlB + (0 * 16 + l15) * 1024 + (kb ^ sw));
            bf8 b1 = *(const bf8*)(WlB + (1 * 16 + l15) * 1024 + (kb ^ sw));
            bf8 b2 = *(const bf8*)(WlB + (2 * 16 + l15) * 1024 + (kb ^ sw));
            bf8 b3 = *(const bf8*)(WlB + (3 * 16 + l15) * 1024 + (kb ^ sw));
            bf8 a0 = *(const bf8*)(xp + k0 + lg * 8);
            bf8 a1 = *(const bf8*)(xp + 16 * EMB + k0 + lg * 8);
            acc[0][0] = __builtin_amdgcn_mfma_f32_16x16x32_bf16(a0, b0, acc[0][0], 0, 0, 0);
            acc[0][1] = __builtin_amdgcn_mfma_f32_16x16x32_bf16(a0, b1, acc[0][1], 0, 0, 0);
            acc[0][2] = __builtin_amdgcn_mfma_f32_16x16x32_bf16(a0, b2, acc[0][2], 0, 0, 0);
            acc[0][3] = __builtin_amdgcn_mfma_f32_16x16x32_bf16(a0, b3, acc[0][3], 0, 0, 0);
            acc[1][0] = __builtin_amdgcn_mfma_f32_16x16x32_bf16(a1, b0, acc[1][0], 0, 0, 0);
            acc[1][1] = __builtin_amdgcn_mfma_f32_16x16x32_bf16(a1, b1, acc[1][1], 0, 0, 0);
            acc[1][2] = __builtin_amdgcn_mfma_f32_16x16x32_bf16(a1, b2, acc[1][2], 0, 0, 0);
            acc[1][3] = __builtin_amdgcn_mfma_f32_16x16x32_bf16(a1, b3, acc[1][3], 0, 0, 0);
        }

        // ---- issue next chunk's global loads (latency hidden by epilogue) ----
        int  cn  = ci + GRID_MAIN;
        bool has = (cn < NBLK);
        float4 st0, st1, st2, st3, st4, st5, st6, st7;
        if (has) {
            int c = cn * BN + cc;
            bool ok = (c < NUM_CLASSES);
            const float4* src = W4 + (size_t)c * 128 + sj;
            float4 z = make_float4(0.f, 0.f, 0.f, 0.f);
            st0 = ok ? src[0]   : z;  st1 = ok ? src[16]  : z;
            st2 = ok ? src[32]  : z;  st3 = ok ? src[48]  : z;
            st4 = ok ? src[64]  : z;  st5 = ok ? src[80]  : z;
            st6 = ok ? src[96]  : z;  st7 = ok ? src[112] : z;
        }

        // ---- epilogue: logits -> per-lane online (M,S) ----
        float rn0 = 1.0f / fmaxf(sqrtf(ssq[buf][0 * 16 + l15]), 1e-12f);
        float rn1 = 1.0f / fmaxf(sqrtf(ssq[buf][1 * 16 + l15]), 1e-12f);
        float rn2 = 1.0f / fmaxf(sqrtf(ssq[buf][2 * 16 + l15]), 1e-12f);
        float rn3 = 1.0f / fmaxf(sqrtf(ssq[buf][3 * 16 + l15]), 1e-12f);
        const int  c0   = ci * BN;
        const bool tail = (c0 + BN > NUM_CLASSES);
#pragma unroll
        for (int mf = 0; mf < 2; ++mf)
#pragma unroll
            for (int i = 0; i < 4; ++i) {
                float v0 = S_SCALE * acc[mf][0][i] * rn0;
                float v1 = S_SCALE * acc[mf][1][i] * rn1;
                float v2 = S_SCALE * acc[mf][2][i] * rn2;
                float v3 = S_SCALE * acc[mf][3][i] * rn3;
                if (tail) {
                    if (c0 + 0 * 16 + l15 >= NUM_CLASSES) v0 = -1e30f;
                    if (c0 + 1 * 16 + l15 >= NUM_CLASSES) v1 = -1e30f;
                    if (c0 + 2 * 16 + l15 >= NUM_CLASSES) v2 = -1e30f;
                    if (c0 + 3 * 16 + l15 >= NUM_CLASSES) v3 = -1e30f;
                }
                float pm = fmaxf(fmaxf(v0, v1), fmaxf(v2, v3));
                float nM = fmaxf(Mr[mf][i], pm);
                Sr[mf][i] = Sr[mf][i] * __expf(Mr[mf][i] - nM)
                          + __expf(v0 - nM) + __expf(v1 - nM)
                          + __expf(v2 - nM) + __expf(v3 - nM);
                Mr[mf][i] = nM;
            }

        // ---- finish stage: convert + swizzled ds_write + ssq ----
        if (has) {
            char* dst = (char*)&Wl[buf ^ 1][0] + cc * 1024;
            float s = 0.f;
            float4 stv[8] = { st0, st1, st2, st3, st4, st5, st6, st7 };
#pragma unroll
            for (int q = 0; q < 8; ++q) {
                float4 v = stv[q];
                s += v.x*v.x + v.y*v.y + v.z*v.z + v.w*v.w;
                int fj = sj + 16 * q;
                *(uint2*)(dst + ((fj * 8) ^ ((cc & 7) << 4))) =
                    make_uint2(f2bf(v.x) | (f2bf(v.y) << 16),
                               f2bf(v.z) | (f2bf(v.w) << 16));
            }
            s += __shfl_xor(s, 1); s += __shfl_xor(s, 2);
            s += __shfl_xor(s, 4); s += __shfl_xor(s, 8);
            if (sj == 0) ssq[buf ^ 1][cc] = s;
        }
        __syncthreads();
        buf ^= 1;
    }

    // ---- final merge across the 16 column-lanes, one write per row ----
#pragma unroll
    for (int mf = 0; mf < 2; ++mf)
#pragma unroll
        for (int i = 0; i < 4; ++i) {
            float M = Mr[mf][i], S = Sr[mf][i];
#pragma unroll
            for (int d = 1; d < 16; d <<= 1) {
                float oM = __shfl_xor(M, d), oS = __shfl_xor(S, d);
                float nM = fmaxf(M, oM);
                S = S * __expf(M - nM) + oS * __expf(oM - nM);
                M = nM;
            }
            if (l15 == 0) {
                int m = wid * 32 + mf * 16 + lg * 4 + i;
                pms[(size_t)blockIdx.x * BATCH + m] = make_float2(M, S);
            }
        }
}

// ---------------------------------------------------------------------------
// k_fin: merge 256 partials per row, patch label column (plain->margin),
// loss, mean -> out[0].
// ---------------------------------------------------------------------------
__global__ __launch_bounds__(512) void k_fin(const float2* __restrict__ pms,
                                             const float* __restrict__ tcos,
                                             const float* __restrict__ tphi,
                                             float* __restrict__ out) {
    int t = threadIdx.x;
    float M = -1e38f, S = 0.f;
    for (int b = 0; b < GRID_MAIN; ++b) {
        float2 v = pms[(size_t)b * BATCH + t];
        float nM = fmaxf(M, v.x);
        S = S * __expf(M - nM) + v.y * __expf(v.x - nM);
        M = nM;
    }
    // replace plain label logit with margin logit in the softmax sum
    float Sc = S - __expf(tcos[t] - M) + __expf(tphi[t] - M);
    Sc = fmaxf(Sc, 1e-30f);
    float loss = M + logf(Sc) - tphi[t];
#pragma unroll
    for (int d = 1; d < 64; d <<= 1) loss += __shfl_xor(loss, d);
    __shared__ float wred[8];
    if ((t & 63) == 0) wred[t >> 6] = loss;
    __syncthreads();
    if (t == 0) {
        float s = 0.f;
        for (int w = 0; w < 8; ++w) s += wred[w];
        out[0] = s / (float)BATCH;
    }
}

extern "C" void kernel_launch(void* const* d_in, const int* in_sizes, int n_in,
                              void* d_out, int out_size, void* d_ws, size_t ws_size,
                              hipStream_t stream) {
    const float*     x     = (const float*)d_in[0];
    const long long* label = (const long long*)d_in[1];
    const float*     W     = (const float*)d_in[2];
    float*           out   = (float*)d_out;

    // workspace layout (~1.6 MB)
    char* ws = (char*)d_ws;
    unsigned short* xb   = (unsigned short*)ws;            // 524288 B
    float*          tcos = (float*)(ws + 524288);          // 2048 B
    float*          tphi = (float*)(ws + 526336);          // 2048 B
    float2*         pms  = (float2*)(ws + 528384);         // 256*512*8 = 1048576 B

    k_normx<<<BATCH / 4, 256,  0, stream>>>(x, xb);
    k_tgt  <<<BATCH / 8, 512,  0, stream>>>(x, W, label, tcos, tphi);
    k_main <<<GRID_MAIN, 1024, 0, stream>>>(W, xb, pms);
    k_fin  <<<1,         512,  0, stream>>>(pms, tcos, tphi, out);
}